// Round 1
// baseline (574.754 us; speedup 1.0000x reference)
//
#include <hip/hip_runtime.h>

// ---------------------------------------------------------------------------
// nGPT attention block on MI355X (gfx950), bf16 MFMA pipeline.
// Sizes: DIM=2048, HEADS=16, DH=128, B=2, S=2048, M=B*S=4096.
// ---------------------------------------------------------------------------

typedef __bf16 bf16x8 __attribute__((ext_vector_type(8)));
typedef float f32x4 __attribute__((ext_vector_type(4)));

__device__ __forceinline__ unsigned short f2bf(float f) {
  unsigned int u = __float_as_uint(f);
  u = u + 0x7FFFu + ((u >> 16) & 1u);   // round-to-nearest-even
  return (unsigned short)(u >> 16);
}

__device__ __forceinline__ void async16(const void* g, void* l) {
  __builtin_amdgcn_global_load_lds(
      (const __attribute__((address_space(1))) unsigned int*)g,
      (__attribute__((address_space(3))) unsigned int*)l, 16, 0, 0);
}

// ---------------------------------------------------------------------------
// Prep kernels
// ---------------------------------------------------------------------------

// Row-l2norm of Wq/Wk/Wv (2048 rows x 2048) -> bf16. grid (2048, 3), block 256.
__global__ __launch_bounds__(256) void prep_w_rows(
    const float* __restrict__ Wq, const float* __restrict__ Wk,
    const float* __restrict__ Wv, ushort* __restrict__ oq,
    ushort* __restrict__ ok_, ushort* __restrict__ ov) {
  const int row = blockIdx.x;
  const float* W = (blockIdx.y == 0) ? Wq : (blockIdx.y == 1) ? Wk : Wv;
  ushort* O = (blockIdx.y == 0) ? oq : (blockIdx.y == 1) ? ok_ : ov;
  const int t = threadIdx.x;
  const float4* Wr = (const float4*)(W + (size_t)row * 2048);
  float4 v0 = Wr[t];
  float4 v1 = Wr[t + 256];
  float ss = v0.x * v0.x + v0.y * v0.y + v0.z * v0.z + v0.w * v0.w +
             v1.x * v1.x + v1.y * v1.y + v1.z * v1.z + v1.w * v1.w;
  ss += __shfl_xor(ss, 1);  ss += __shfl_xor(ss, 2);
  ss += __shfl_xor(ss, 4);  ss += __shfl_xor(ss, 8);
  ss += __shfl_xor(ss, 16); ss += __shfl_xor(ss, 32);
  __shared__ float red[4];
  if ((t & 63) == 0) red[t >> 6] = ss;
  __syncthreads();
  float tot = red[0] + red[1] + red[2] + red[3];
  float sc = 1.0f / fmaxf(sqrtf(tot), 1e-12f);
  ushort4 o0, o1;
  o0.x = f2bf(v0.x * sc); o0.y = f2bf(v0.y * sc);
  o0.z = f2bf(v0.z * sc); o0.w = f2bf(v0.w * sc);
  o1.x = f2bf(v1.x * sc); o1.y = f2bf(v1.y * sc);
  o1.z = f2bf(v1.z * sc); o1.w = f2bf(v1.w * sc);
  *(ushort4*)(O + (size_t)row * 2048 + t * 4) = o0;
  *(ushort4*)(O + (size_t)row * 2048 + 1024 + t * 4) = o1;
}

// Wout column sum-of-squares. grid (8, 16), block 256. colss pre-zeroed.
__global__ __launch_bounds__(256) void wout_colss(const float* __restrict__ W,
                                                  float* __restrict__ colss) {
  const int e = blockIdx.x * 256 + threadIdx.x;
  const int d0 = blockIdx.y * 128;
  float ss = 0.f;
  #pragma unroll 8
  for (int i = 0; i < 128; ++i) {
    float v = W[(size_t)(d0 + i) * 2048 + e];
    ss += v * v;
  }
  atomicAdd(colss + e, ss);
}

// Wout / colnorm -> bf16. grid 4096, block 256, 4 elems/thread.
__global__ __launch_bounds__(256) void wout_norm(const float* __restrict__ W,
                                                 const float* __restrict__ colss,
                                                 ushort* __restrict__ O) {
  const int idx = (blockIdx.x * 256 + threadIdx.x) * 4;
  float4 v = *(const float4*)(W + idx);
  float4 c = *(const float4*)(colss + (idx & 2047));
  ushort4 o;
  o.x = f2bf(v.x / fmaxf(sqrtf(c.x), 1e-12f));
  o.y = f2bf(v.y / fmaxf(sqrtf(c.y), 1e-12f));
  o.z = f2bf(v.z / fmaxf(sqrtf(c.z), 1e-12f));
  o.w = f2bf(v.w / fmaxf(sqrtf(c.w), 1e-12f));
  *(ushort4*)(O + idx) = o;
}

// x fp32 -> bf16. grid 8192, block 256, 4 elems/thread (8M total).
__global__ __launch_bounds__(256) void convert_x(const float* __restrict__ X,
                                                 ushort* __restrict__ O) {
  const int idx = (blockIdx.x * 256 + threadIdx.x) * 4;
  float4 v = *(const float4*)(X + idx);
  ushort4 o;
  o.x = f2bf(v.x); o.y = f2bf(v.y); o.z = f2bf(v.z); o.w = f2bf(v.w);
  *(ushort4*)(O + idx) = o;
}

// ---------------------------------------------------------------------------
// Shared GEMM mainloop: C[128x128] tile = A[128xK] * B[128xK]^T, K=2048, BK=32.
// m97 structure: global_load_lds width-16, 2 barriers/iter, 16 MFMA/wave/iter.
// ---------------------------------------------------------------------------
__device__ __forceinline__ void gemm_mainloop(
    const ushort* __restrict__ A, const ushort* __restrict__ Bw,
    int m0, int n0, ushort* As, ushort* Bs, f32x4 acc[4][4],
    int t, int l, int wm, int wn) {
  const int r0 = t >> 2, kc = t & 3;
  const int l15 = l & 15, l4 = l >> 4;
  for (int kt = 0; kt < 64; ++kt) {
    const int k0 = kt * 32;
    __syncthreads();
    async16(A + (size_t)(m0 + r0) * 2048 + k0 + kc * 8,       (char*)As + t * 16);
    async16(A + (size_t)(m0 + 64 + r0) * 2048 + k0 + kc * 8,  (char*)As + 4096 + t * 16);
    async16(Bw + (size_t)(n0 + r0) * 2048 + k0 + kc * 8,      (char*)Bs + t * 16);
    async16(Bw + (size_t)(n0 + 64 + r0) * 2048 + k0 + kc * 8, (char*)Bs + 4096 + t * 16);
    __syncthreads();
    bf16x8 af[4], bg[4];
    #pragma unroll
    for (int f = 0; f < 4; ++f)
      af[f] = *(const bf16x8*)&As[(wm * 64 + f * 16 + l15) * 32 + l4 * 8];
    #pragma unroll
    for (int f = 0; f < 4; ++f)
      bg[f] = *(const bf16x8*)&Bs[(wn * 64 + f * 16 + l15) * 32 + l4 * 8];
    #pragma unroll
    for (int fm = 0; fm < 4; ++fm)
      #pragma unroll
      for (int fn = 0; fn < 4; ++fn)
        acc[fm][fn] = __builtin_amdgcn_mfma_f32_16x16x32_bf16(
            af[fm], bg[fn], acc[fm][fn], 0, 0, 0);
  }
}

// ---------------------------------------------------------------------------
// QKV GEMM with fused per-head l2norm epilogue.
// grid (16 n-tiles, 32 m-tiles, 3 weights). N-tile 128 == one head exactly.
// z=0: q -> l2norm * qk_scale*DIM*sqrt(128), bf16 [m][e]
// z=1: k -> l2norm, bf16 [m][e]
// z=2: v -> bf16 transposed [b,h,d][n]
// ---------------------------------------------------------------------------
__global__ __launch_bounds__(256) void gemm_qkv(
    const ushort* __restrict__ X, const ushort* __restrict__ Wq,
    const ushort* __restrict__ Wk, const ushort* __restrict__ Wv,
    const float* __restrict__ qks, ushort* __restrict__ qn,
    ushort* __restrict__ kn, ushort* __restrict__ vt) {
  const int z = blockIdx.z;
  const ushort* Bw = (z == 0) ? Wq : (z == 1) ? Wk : Wv;
  const int n0 = blockIdx.x * 128;
  const int m0 = blockIdx.y * 128;
  __shared__ __align__(16) ushort As[128 * 32];
  __shared__ __align__(16) ushort Bs[128 * 32];
  __shared__ float partials[2][128];
  const int t = threadIdx.x, w = t >> 6, l = t & 63;
  const int wm = w & 1, wn = w >> 1;
  const int l15 = l & 15, l4 = l >> 4;

  f32x4 acc[4][4];
  #pragma unroll
  for (int i = 0; i < 4; ++i)
    #pragma unroll
    for (int j = 0; j < 4; ++j) acc[i][j] = (f32x4){0.f, 0.f, 0.f, 0.f};

  gemm_mainloop(X, Bw, m0, n0, As, Bs, acc, t, l, wm, wn);

  const int h = n0 >> 7;
  if (z == 2) {
    // write V transposed: vt[(b*16+h)*128 + d][n], pack 4 consecutive n (rows)
    #pragma unroll
    for (int fm = 0; fm < 4; ++fm) {
      int mrow = m0 + wm * 64 + fm * 16 + l4 * 4;
      int bb = mrow >> 11;
      int nn = mrow & 2047;
      #pragma unroll
      for (int fn = 0; fn < 4; ++fn) {
        int d = wn * 64 + fn * 16 + l15;
        ushort4 p;
        p.x = f2bf(acc[fm][fn][0]); p.y = f2bf(acc[fm][fn][1]);
        p.z = f2bf(acc[fm][fn][2]); p.w = f2bf(acc[fm][fn][3]);
        *(ushort4*)(vt + (size_t)((bb * 16 + h) * 128 + d) * 2048 + nn) = p;
      }
    }
  } else {
    // per-row (per-head) sum of squares across the 128 cols of this tile
    float rs[4][4];
    #pragma unroll
    for (int fm = 0; fm < 4; ++fm)
      #pragma unroll
      for (int r = 0; r < 4; ++r) {
        float s = 0.f;
        #pragma unroll
        for (int fn = 0; fn < 4; ++fn) {
          float v = acc[fm][fn][r];
          s += v * v;
        }
        s += __shfl_xor(s, 1); s += __shfl_xor(s, 2);
        s += __shfl_xor(s, 4); s += __shfl_xor(s, 8);
        rs[fm][r] = s;
      }
    if (l15 == 0) {
      #pragma unroll
      for (int fm = 0; fm < 4; ++fm)
        #pragma unroll
        for (int r = 0; r < 4; ++r)
          partials[wn][wm * 64 + fm * 16 + l4 * 4 + r] = rs[fm][r];
    }
    __syncthreads();
    float cs[4];
    #pragma unroll
    for (int fn = 0; fn < 4; ++fn)
      cs[fn] = (z == 0)
                   ? qks[n0 + wn * 64 + fn * 16 + l15] * (2048.0f * 11.313708498984761f)
                   : 1.0f;
    ushort* O = (z == 0) ? qn : kn;
    #pragma unroll
    for (int fm = 0; fm < 4; ++fm)
      #pragma unroll
      for (int r = 0; r < 4; ++r) {
        int i = wm * 64 + fm * 16 + l4 * 4 + r;
        float tot = partials[0][i] + partials[1][i];
        float sc = 1.0f / fmaxf(sqrtf(tot), 1e-12f);
        #pragma unroll
        for (int fn = 0; fn < 4; ++fn)
          O[(size_t)(m0 + i) * 2048 + n0 + wn * 64 + fn * 16 + l15] =
              f2bf(acc[fm][fn][r] * sc * cs[fn]);
      }
  }
}

// ---------------------------------------------------------------------------
// Causal flash attention. grid (16 q-tiles, 16 heads, 2 batch), block 256.
// Q-tile 128 (in registers), KV-tile 64. Online softmax. P via padded LDS.
// ---------------------------------------------------------------------------
__global__ __launch_bounds__(256) void attn_kernel(
    const ushort* __restrict__ qn, const ushort* __restrict__ kn,
    const ushort* __restrict__ vt, ushort* __restrict__ ao) {
  const int qt = blockIdx.x, h = blockIdx.y, b = blockIdx.z;
  const int i0 = qt * 128;
  const int t = threadIdx.x, w = t >> 6, l = t & 63;
  const int l15 = l & 15, l4 = l >> 4;

  // Padded-row LDS: Ks rows = 17 x 16B chunks (16 data + 1 pad) -> 272B stride
  //                 Vts rows = 9 chunks (8 data + 1 pad)        -> 144B stride
  __shared__ __align__(16) ushort Ks[64 * 136];
  __shared__ __align__(16) ushort Vts[128 * 72];
  __shared__ __align__(16) ushort Ps[128 * 72];

  // Q fragments (A-operand layout): rows i = w*32 + fi*16 + l15, k = ks*32+l4*8
  bf16x8 qf[2][4];
  #pragma unroll
  for (int fi = 0; fi < 2; ++fi)
    #pragma unroll
    for (int ks = 0; ks < 4; ++ks)
      qf[fi][ks] = *(const bf16x8*)(qn +
          (size_t)(b * 2048 + i0 + w * 32 + fi * 16 + l15) * 2048 +
          h * 128 + ks * 32 + l4 * 8);

  f32x4 Oa[2][8];
  #pragma unroll
  for (int fi = 0; fi < 2; ++fi)
    #pragma unroll
    for (int fd = 0; fd < 8; ++fd) Oa[fi][fd] = (f32x4){0.f, 0.f, 0.f, 0.f};
  float mrow[2][4], lrow[2][4];
  #pragma unroll
  for (int fi = 0; fi < 2; ++fi)
    #pragma unroll
    for (int r = 0; r < 4; ++r) { mrow[fi][r] = -1e30f; lrow[fi][r] = 0.f; }

  const ushort* kbase = kn + (size_t)(b * 2048) * 2048 + h * 128;
  const ushort* vbase = vt + (size_t)((b * 16 + h) * 128) * 2048;
  const int jt_end = 2 * qt + 2;

  for (int jt = 0; jt < jt_end; ++jt) {
    const int j0 = jt * 64;
    __syncthreads();
    // Stage K tile: 64 rows x (16+1) chunks = 1088 chunks
    #pragma unroll
    for (int pass = 0; pass < 5; ++pass) {
      int c = pass * 256 + t;
      if (c < 1088) {
        int r = c / 17, dc = c - r * 17;
        int dcc = (dc == 16) ? 0 : dc;
        async16(kbase + (size_t)(j0 + r) * 2048 + dcc * 8, (char*)Ks + c * 16);
      }
    }
    // Stage V^T tile: 128 rows x (8+1) chunks = 1152 chunks
    #pragma unroll
    for (int pass = 0; pass < 5; ++pass) {
      int c = pass * 256 + t;
      if (c < 1152) {
        int r = c / 9, jc = c - r * 9;
        int jcc = (jc == 8) ? 0 : jc;
        async16(vbase + (size_t)r * 2048 + j0 + jcc * 8, (char*)Vts + c * 16);
      }
    }
    __syncthreads();

    // S = Q K^T  (scale already folded into q)
    f32x4 Sa[2][4];
    #pragma unroll
    for (int fj = 0; fj < 4; ++fj) {
      f32x4 s0 = (f32x4){0.f, 0.f, 0.f, 0.f};
      f32x4 s1 = (f32x4){0.f, 0.f, 0.f, 0.f};
      #pragma unroll
      for (int ks = 0; ks < 4; ++ks) {
        bf16x8 kf = *(const bf16x8*)&Ks[(fj * 16 + l15) * 136 + ks * 32 + l4 * 8];
        s0 = __builtin_amdgcn_mfma_f32_16x16x32_bf16(qf[0][ks], kf, s0, 0, 0, 0);
        s1 = __builtin_amdgcn_mfma_f32_16x16x32_bf16(qf[1][ks], kf, s1, 0, 0, 0);
      }
      Sa[0][fj] = s0; Sa[1][fj] = s1;
    }

    // Causal mask on the two diagonal-crossing tiles
    if (jt >= 2 * qt) {
      #pragma unroll
      for (int fi = 0; fi < 2; ++fi)
        #pragma unroll
        for (int fj = 0; fj < 4; ++fj)
          #pragma unroll
          for (int r = 0; r < 4; ++r) {
            int jg = j0 + fj * 16 + l15;
            int ig = i0 + w * 32 + fi * 16 + l4 * 4 + r;
            if (jg > ig) Sa[fi][fj][r] = -1e30f;
          }
    }

    // Online softmax (rows shared across the 16-lane col group)
    #pragma unroll
    for (int fi = 0; fi < 2; ++fi)
      #pragma unroll
      for (int r = 0; r < 4; ++r) {
        float mx = fmaxf(fmaxf(Sa[fi][0][r], Sa[fi][1][r]),
                         fmaxf(Sa[fi][2][r], Sa[fi][3][r]));
        mx = fmaxf(mx, __shfl_xor(mx, 1)); mx = fmaxf(mx, __shfl_xor(mx, 2));
        mx = fmaxf(mx, __shfl_xor(mx, 4)); mx = fmaxf(mx, __shfl_xor(mx, 8));
        float mnew = fmaxf(mrow[fi][r], mx);
        float al = __expf(mrow[fi][r] - mnew);
        mrow[fi][r] = mnew;
        float rsum = 0.f;
        #pragma unroll
        for (int fj = 0; fj < 4; ++fj) {
          float p = __expf(Sa[fi][fj][r] - mnew);
          Sa[fi][fj][r] = p;
          rsum += p;
        }
        rsum += __shfl_xor(rsum, 1); rsum += __shfl_xor(rsum, 2);
        rsum += __shfl_xor(rsum, 4); rsum += __shfl_xor(rsum, 8);
        lrow[fi][r] = lrow[fi][r] * al + rsum;
        #pragma unroll
        for (int fd = 0; fd < 8; ++fd) Oa[fi][fd][r] *= al;
      }

    // P -> LDS (C-layout scatter; rows are wave-private, no barrier needed)
    #pragma unroll
    for (int fi = 0; fi < 2; ++fi)
      #pragma unroll
      for (int fj = 0; fj < 4; ++fj)
        #pragma unroll
        for (int r = 0; r < 4; ++r)
          Ps[(w * 32 + fi * 16 + l4 * 4 + r) * 72 + fj * 16 + l15] =
              f2bf(Sa[fi][fj][r]);

    // O += P V
    #pragma unroll
    for (int ks = 0; ks < 2; ++ks) {
      bf16x8 p0 = *(const bf16x8*)&Ps[(w * 32 + l15) * 72 + ks * 32 + l4 * 8];
      bf16x8 p1 = *(const bf16x8*)&Ps[(w * 32 + 16 + l15) * 72 + ks * 32 + l4 * 8];
      #pragma unroll
      for (int fd = 0; fd < 8; ++fd) {
        bf16x8 vf = *(const bf16x8*)&Vts[(fd * 16 + l15) * 72 + ks * 32 + l4 * 8];
        Oa[0][fd] = __builtin_amdgcn_mfma_f32_16x16x32_bf16(p0, vf, Oa[0][fd], 0, 0, 0);
        Oa[1][fd] = __builtin_amdgcn_mfma_f32_16x16x32_bf16(p1, vf, Oa[1][fd], 0, 0, 0);
      }
    }
  }

  // Epilogue: O /= l, write bf16 [m][e]
  #pragma unroll
  for (int fi = 0; fi < 2; ++fi)
    #pragma unroll
    for (int r = 0; r < 4; ++r) {
      float inv = 1.0f / lrow[fi][r];
      int ig = i0 + w * 32 + fi * 16 + l4 * 4 + r;
      #pragma unroll
      for (int fd = 0; fd < 8; ++fd)
        ao[(size_t)(b * 2048 + ig) * 2048 + h * 128 + fd * 16 + l15] =
            f2bf(Oa[fi][fd][r] * inv);
    }
}

// ---------------------------------------------------------------------------
// Output GEMM: out[m][d] = sum_e ao[m][e] * WoutN[d][e], fp32 out.
// ---------------------------------------------------------------------------
__global__ __launch_bounds__(256) void gemm_out(
    const ushort* __restrict__ A, const ushort* __restrict__ Bw,
    float* __restrict__ C) {
  const int n0 = blockIdx.x * 128;
  const int m0 = blockIdx.y * 128;
  __shared__ __align__(16) ushort As[128 * 32];
  __shared__ __align__(16) ushort Bs[128 * 32];
  const int t = threadIdx.x, w = t >> 6, l = t & 63;
  const int wm = w & 1, wn = w >> 1;
  const int l15 = l & 15, l4 = l >> 4;

  f32x4 acc[4][4];
  #pragma unroll
  for (int i = 0; i < 4; ++i)
    #pragma unroll
    for (int j = 0; j < 4; ++j) acc[i][j] = (f32x4){0.f, 0.f, 0.f, 0.f};

  gemm_mainloop(A, Bw, m0, n0, As, Bs, acc, t, l, wm, wn);

  #pragma unroll
  for (int fm = 0; fm < 4; ++fm)
    #pragma unroll
    for (int fn = 0; fn < 4; ++fn)
      #pragma unroll
      for (int r = 0; r < 4; ++r)
        C[(size_t)(m0 + wm * 64 + fm * 16 + l4 * 4 + r) * 2048 +
          n0 + wn * 64 + fn * 16 + l15] = acc[fm][fn][r];
}

// ---------------------------------------------------------------------------
// Launch
// ---------------------------------------------------------------------------
extern "C" void kernel_launch(void* const* d_in, const int* in_sizes, int n_in,
                              void* d_out, int out_size, void* d_ws, size_t ws_size,
                              hipStream_t stream) {
  (void)in_sizes; (void)n_in; (void)out_size; (void)ws_size;
  const float* x    = (const float*)d_in[0];
  const float* Wq   = (const float*)d_in[1];
  const float* Wk   = (const float*)d_in[2];
  const float* Wv   = (const float*)d_in[3];
  const float* Wout = (const float*)d_in[4];
  const float* qks  = (const float*)d_in[5];
  char* ws = (char*)d_ws;

  // workspace layout (bytes)
  ushort* wqn  = (ushort*)(ws + 0);           //  8 MB
  ushort* wkn  = (ushort*)(ws + 8388608);     //  8 MB
  ushort* wvn  = (ushort*)(ws + 16777216);    //  8 MB
  ushort* wotn = (ushort*)(ws + 25165824);    //  8 MB
  ushort* xbf  = (ushort*)(ws + 33554432);    // 16 MB
  ushort* qn   = (ushort*)(ws + 50331648);    // 16 MB
  ushort* kn   = (ushort*)(ws + 67108864);    // 16 MB
  ushort* vt   = (ushort*)(ws + 83886080);    // 16 MB
  ushort* ao   = (ushort*)(ws + 100663296);   // 16 MB
  float* colss = (float*)(ws + 117440512);    //  8 KB
  float* out   = (float*)d_out;

  hipMemsetAsync(colss, 0, 2048 * sizeof(float), stream);
  prep_w_rows<<<dim3(2048, 3), 256, 0, stream>>>(Wq, Wk, Wv, wqn, wkn, wvn);
  wout_colss<<<dim3(8, 16), 256, 0, stream>>>(Wout, colss);
  wout_norm<<<4096, 256, 0, stream>>>(Wout, colss, wotn);
  convert_x<<<8192, 256, 0, stream>>>(x, xbf);
  gemm_qkv<<<dim3(16, 32, 3), 256, 0, stream>>>(xbf, wqn, wkn, wvn, qks, qn, kn, vt);
  attn_kernel<<<dim3(16, 16, 2), 256, 0, stream>>>(qn, kn, vt, ao);
  gemm_out<<<dim3(16, 32), 256, 0, stream>>>(ao, wotn, out);
}

// Round 2
// 420.574 us; speedup vs baseline: 1.3666x; 1.3666x over previous
//
#include <hip/hip_runtime.h>

// ---------------------------------------------------------------------------
// nGPT attention block on MI355X (gfx950), bf16 MFMA pipeline.
// Sizes: DIM=2048, HEADS=16, DH=128, B=2, S=2048, M=B*S=4096.
// ---------------------------------------------------------------------------

typedef __bf16 bf16x8 __attribute__((ext_vector_type(8)));
typedef float f32x4 __attribute__((ext_vector_type(4)));

__device__ __forceinline__ unsigned short f2bf(float f) {
  unsigned int u = __float_as_uint(f);
  u = u + 0x7FFFu + ((u >> 16) & 1u);   // round-to-nearest-even
  return (unsigned short)(u >> 16);
}

__device__ __forceinline__ void async16(const void* g, void* l) {
  __builtin_amdgcn_global_load_lds(
      (const __attribute__((address_space(1))) unsigned int*)g,
      (__attribute__((address_space(3))) unsigned int*)l, 16, 0, 0);
}

// scale folded into q: qk_scale * DIM * sqrt(DH) * log2(e)
#define QFOLD (2048.0f * 11.313708498984761f * 1.4426950408889634f)

// ---------------------------------------------------------------------------
// Prep kernels
// ---------------------------------------------------------------------------

// Row-l2norm of Wq/Wk/Wv (2048 rows x 2048) -> bf16. grid (2048, 3), block 256.
__global__ __launch_bounds__(256) void prep_w_rows(
    const float* __restrict__ Wq, const float* __restrict__ Wk,
    const float* __restrict__ Wv, ushort* __restrict__ oq,
    ushort* __restrict__ ok_, ushort* __restrict__ ov) {
  const int row = blockIdx.x;
  const float* W = (blockIdx.y == 0) ? Wq : (blockIdx.y == 1) ? Wk : Wv;
  ushort* O = (blockIdx.y == 0) ? oq : (blockIdx.y == 1) ? ok_ : ov;
  const int t = threadIdx.x;
  const float4* Wr = (const float4*)(W + (size_t)row * 2048);
  float4 v0 = Wr[t];
  float4 v1 = Wr[t + 256];
  float ss = v0.x * v0.x + v0.y * v0.y + v0.z * v0.z + v0.w * v0.w +
             v1.x * v1.x + v1.y * v1.y + v1.z * v1.z + v1.w * v1.w;
  ss += __shfl_xor(ss, 1);  ss += __shfl_xor(ss, 2);
  ss += __shfl_xor(ss, 4);  ss += __shfl_xor(ss, 8);
  ss += __shfl_xor(ss, 16); ss += __shfl_xor(ss, 32);
  __shared__ float red[4];
  if ((t & 63) == 0) red[t >> 6] = ss;
  __syncthreads();
  float tot = red[0] + red[1] + red[2] + red[3];
  float sc = 1.0f / fmaxf(sqrtf(tot), 1e-12f);
  ushort4 o0, o1;
  o0.x = f2bf(v0.x * sc); o0.y = f2bf(v0.y * sc);
  o0.z = f2bf(v0.z * sc); o0.w = f2bf(v0.w * sc);
  o1.x = f2bf(v1.x * sc); o1.y = f2bf(v1.y * sc);
  o1.z = f2bf(v1.z * sc); o1.w = f2bf(v1.w * sc);
  *(ushort4*)(O + (size_t)row * 2048 + t * 4) = o0;
  *(ushort4*)(O + (size_t)row * 2048 + 1024 + t * 4) = o1;
}

// Wout column sum-of-squares. grid (8, 16), block 256. colss pre-zeroed.
__global__ __launch_bounds__(256) void wout_colss(const float* __restrict__ W,
                                                  float* __restrict__ colss) {
  const int e = blockIdx.x * 256 + threadIdx.x;
  const int d0 = blockIdx.y * 128;
  float ss = 0.f;
  #pragma unroll 8
  for (int i = 0; i < 128; ++i) {
    float v = W[(size_t)(d0 + i) * 2048 + e];
    ss += v * v;
  }
  atomicAdd(colss + e, ss);
}

// Wout / colnorm -> bf16. grid 4096, block 256, 4 elems/thread.
__global__ __launch_bounds__(256) void wout_norm(const float* __restrict__ W,
                                                 const float* __restrict__ colss,
                                                 ushort* __restrict__ O) {
  const int idx = (blockIdx.x * 256 + threadIdx.x) * 4;
  float4 v = *(const float4*)(W + idx);
  float4 c = *(const float4*)(colss + (idx & 2047));
  ushort4 o;
  o.x = f2bf(v.x / fmaxf(sqrtf(c.x), 1e-12f));
  o.y = f2bf(v.y / fmaxf(sqrtf(c.y), 1e-12f));
  o.z = f2bf(v.z / fmaxf(sqrtf(c.z), 1e-12f));
  o.w = f2bf(v.w / fmaxf(sqrtf(c.w), 1e-12f));
  *(ushort4*)(O + idx) = o;
}

// x fp32 -> bf16. grid 8192, block 256, 4 elems/thread (8M total).
__global__ __launch_bounds__(256) void convert_x(const float* __restrict__ X,
                                                 ushort* __restrict__ O) {
  const int idx = (blockIdx.x * 256 + threadIdx.x) * 4;
  float4 v = *(const float4*)(X + idx);
  ushort4 o;
  o.x = f2bf(v.x); o.y = f2bf(v.y); o.z = f2bf(v.z); o.w = f2bf(v.w);
  *(ushort4*)(O + idx) = o;
}

// Per-head softmax max-bound: m[h] = QFOLD * max_d |qks[h*128+d]|.
// grid 16, block 64.
__global__ __launch_bounds__(64) void qk_mhead(const float* __restrict__ qks,
                                               float* __restrict__ mh) {
  const int h = blockIdx.x, l = threadIdx.x;
  float m = fmaxf(fabsf(qks[h * 128 + l]), fabsf(qks[h * 128 + 64 + l]));
  m = fmaxf(m, __shfl_xor(m, 1));  m = fmaxf(m, __shfl_xor(m, 2));
  m = fmaxf(m, __shfl_xor(m, 4));  m = fmaxf(m, __shfl_xor(m, 8));
  m = fmaxf(m, __shfl_xor(m, 16)); m = fmaxf(m, __shfl_xor(m, 32));
  if (l == 0) mh[h] = m * QFOLD;
}

// ---------------------------------------------------------------------------
// Shared GEMM mainloop: C[128x128] tile = A[128xK] * B[128xK]^T, K=2048, BK=32.
// ---------------------------------------------------------------------------
__device__ __forceinline__ void gemm_mainloop(
    const ushort* __restrict__ A, const ushort* __restrict__ Bw,
    int m0, int n0, ushort* As, ushort* Bs, f32x4 acc[4][4],
    int t, int l, int wm, int wn) {
  const int r0 = t >> 2, kc = t & 3;
  const int l15 = l & 15, l4 = l >> 4;
  for (int kt = 0; kt < 64; ++kt) {
    const int k0 = kt * 32;
    __syncthreads();
    async16(A + (size_t)(m0 + r0) * 2048 + k0 + kc * 8,       (char*)As + t * 16);
    async16(A + (size_t)(m0 + 64 + r0) * 2048 + k0 + kc * 8,  (char*)As + 4096 + t * 16);
    async16(Bw + (size_t)(n0 + r0) * 2048 + k0 + kc * 8,      (char*)Bs + t * 16);
    async16(Bw + (size_t)(n0 + 64 + r0) * 2048 + k0 + kc * 8, (char*)Bs + 4096 + t * 16);
    __syncthreads();
    bf16x8 af[4], bg[4];
    #pragma unroll
    for (int f = 0; f < 4; ++f)
      af[f] = *(const bf16x8*)&As[(wm * 64 + f * 16 + l15) * 32 + l4 * 8];
    #pragma unroll
    for (int f = 0; f < 4; ++f)
      bg[f] = *(const bf16x8*)&Bs[(wn * 64 + f * 16 + l15) * 32 + l4 * 8];
    #pragma unroll
    for (int fm = 0; fm < 4; ++fm)
      #pragma unroll
      for (int fn = 0; fn < 4; ++fn)
        acc[fm][fn] = __builtin_amdgcn_mfma_f32_16x16x32_bf16(
            af[fm], bg[fn], acc[fm][fn], 0, 0, 0);
  }
}

// ---------------------------------------------------------------------------
// QKV GEMM with fused per-head l2norm epilogue.
// z=0: q -> l2norm * qk_scale*DIM*sqrt(128)*log2e, bf16 [m][e]
// z=1: k -> l2norm, bf16 [m][e]
// z=2: v -> bf16 transposed [b,h,d][n]
// ---------------------------------------------------------------------------
__global__ __launch_bounds__(256) void gemm_qkv(
    const ushort* __restrict__ X, const ushort* __restrict__ Wq,
    const ushort* __restrict__ Wk, const ushort* __restrict__ Wv,
    const float* __restrict__ qks, ushort* __restrict__ qn,
    ushort* __restrict__ kn, ushort* __restrict__ vt) {
  const int z = blockIdx.z;
  const ushort* Bw = (z == 0) ? Wq : (z == 1) ? Wk : Wv;
  const int n0 = blockIdx.x * 128;
  const int m0 = blockIdx.y * 128;
  __shared__ __align__(16) ushort As[128 * 32];
  __shared__ __align__(16) ushort Bs[128 * 32];
  __shared__ float partials[2][128];
  const int t = threadIdx.x, w = t >> 6, l = t & 63;
  const int wm = w & 1, wn = w >> 1;
  const int l15 = l & 15, l4 = l >> 4;

  f32x4 acc[4][4];
  #pragma unroll
  for (int i = 0; i < 4; ++i)
    #pragma unroll
    for (int j = 0; j < 4; ++j) acc[i][j] = (f32x4){0.f, 0.f, 0.f, 0.f};

  gemm_mainloop(X, Bw, m0, n0, As, Bs, acc, t, l, wm, wn);

  const int h = n0 >> 7;
  if (z == 2) {
    #pragma unroll
    for (int fm = 0; fm < 4; ++fm) {
      int mrow = m0 + wm * 64 + fm * 16 + l4 * 4;
      int bb = mrow >> 11;
      int nn = mrow & 2047;
      #pragma unroll
      for (int fn = 0; fn < 4; ++fn) {
        int d = wn * 64 + fn * 16 + l15;
        ushort4 p;
        p.x = f2bf(acc[fm][fn][0]); p.y = f2bf(acc[fm][fn][1]);
        p.z = f2bf(acc[fm][fn][2]); p.w = f2bf(acc[fm][fn][3]);
        *(ushort4*)(vt + (size_t)((bb * 16 + h) * 128 + d) * 2048 + nn) = p;
      }
    }
  } else {
    float rs[4][4];
    #pragma unroll
    for (int fm = 0; fm < 4; ++fm)
      #pragma unroll
      for (int r = 0; r < 4; ++r) {
        float s = 0.f;
        #pragma unroll
        for (int fn = 0; fn < 4; ++fn) {
          float v = acc[fm][fn][r];
          s += v * v;
        }
        s += __shfl_xor(s, 1); s += __shfl_xor(s, 2);
        s += __shfl_xor(s, 4); s += __shfl_xor(s, 8);
        rs[fm][r] = s;
      }
    if (l15 == 0) {
      #pragma unroll
      for (int fm = 0; fm < 4; ++fm)
        #pragma unroll
        for (int r = 0; r < 4; ++r)
          partials[wn][wm * 64 + fm * 16 + l4 * 4 + r] = rs[fm][r];
    }
    __syncthreads();
    float cs[4];
    #pragma unroll
    for (int fn = 0; fn < 4; ++fn)
      cs[fn] = (z == 0) ? qks[n0 + wn * 64 + fn * 16 + l15] * QFOLD : 1.0f;
    ushort* O = (z == 0) ? qn : kn;
    #pragma unroll
    for (int fm = 0; fm < 4; ++fm)
      #pragma unroll
      for (int r = 0; r < 4; ++r) {
        int i = wm * 64 + fm * 16 + l4 * 4 + r;
        float tot = partials[0][i] + partials[1][i];
        float sc = 1.0f / fmaxf(sqrtf(tot), 1e-12f);
        #pragma unroll
        for (int fn = 0; fn < 4; ++fn)
          O[(size_t)(m0 + i) * 2048 + n0 + wn * 64 + fn * 16 + l15] =
              f2bf(acc[fm][fn][r] * sc * cs[fn]);
      }
  }
}

// ---------------------------------------------------------------------------
// Causal flash attention, fixed-m softmax (m bounded per head from qk_scale).
// grid (hb=32, qtile=32) with qt reversed (heavy blocks dispatch first).
// 64-row Q tiles (16 rows/wave), KV-tile 64. No shuffles, no rescale; row-sum
// l via an extra MFMA against an all-ones B fragment.
// ---------------------------------------------------------------------------
__global__ __launch_bounds__(256, 3) void attn_kernel(
    const ushort* __restrict__ qn, const ushort* __restrict__ kn,
    const ushort* __restrict__ vt, const float* __restrict__ mhead,
    ushort* __restrict__ ao) {
  const int hb = blockIdx.x;
  const int b = hb >> 4, h = hb & 15;
  const int qt = 31 - blockIdx.y;          // LPT: heavy first
  const int i0 = qt * 64;
  const int t = threadIdx.x, w = t >> 6, l = t & 63;
  const int l15 = l & 15, l4 = l >> 4;

  // Padded-row LDS: Ks rows = 17 x 16B chunks -> 272B stride
  //                 Vts/Ps rows = 9 chunks    -> 144B stride
  __shared__ __align__(16) ushort Ks[64 * 136];
  __shared__ __align__(16) ushort Vts[128 * 72];
  __shared__ __align__(16) ushort Ps[64 * 72];

  // Q fragments (A-operand layout): row i = w*16 + l15, k = ks*32 + l4*8
  bf16x8 qf[4];
  #pragma unroll
  for (int ks = 0; ks < 4; ++ks)
    qf[ks] = *(const bf16x8*)(qn +
        (size_t)(b * 2048 + i0 + w * 16 + l15) * 2048 +
        h * 128 + ks * 32 + l4 * 8);

  f32x4 Oa[8];
  #pragma unroll
  for (int fd = 0; fd < 8; ++fd) Oa[fd] = (f32x4){0.f, 0.f, 0.f, 0.f};
  f32x4 Ol = (f32x4){0.f, 0.f, 0.f, 0.f};

  const float mh = mhead[h];
  const __bf16 one = (__bf16)1.0f;
  const bf16x8 ones = {one, one, one, one, one, one, one, one};

  const ushort* kbase = kn + (size_t)(b * 2048) * 2048 + h * 128;
  const ushort* vbase = vt + (size_t)((b * 16 + h) * 128) * 2048;

  for (int jt = 0; jt <= qt; ++jt) {
    const int j0 = jt * 64;
    __syncthreads();
    // Stage K tile: 64 rows x (16+1) chunks = 1088
    #pragma unroll
    for (int pass = 0; pass < 5; ++pass) {
      int c = pass * 256 + t;
      if (c < 1088) {
        int r = c / 17, dc = c - r * 17;
        int dcc = (dc == 16) ? 0 : dc;
        async16(kbase + (size_t)(j0 + r) * 2048 + dcc * 8, (char*)Ks + c * 16);
      }
    }
    // Stage V^T tile: 128 rows x (8+1) chunks = 1152
    #pragma unroll
    for (int pass = 0; pass < 5; ++pass) {
      int c = pass * 256 + t;
      if (c < 1152) {
        int r = c / 9, jc = c - r * 9;
        int jcc = (jc == 8) ? 0 : jc;
        async16(vbase + (size_t)r * 2048 + j0 + jcc * 8, (char*)Vts + c * 16);
      }
    }
    __syncthreads();

    // S' = Q' K^T   (log2e etc. folded into q)
    f32x4 Sa[4];
    #pragma unroll
    for (int fj = 0; fj < 4; ++fj) {
      f32x4 s0 = (f32x4){0.f, 0.f, 0.f, 0.f};
      #pragma unroll
      for (int ks = 0; ks < 4; ++ks) {
        bf16x8 kf = *(const bf16x8*)&Ks[(fj * 16 + l15) * 136 + ks * 32 + l4 * 8];
        s0 = __builtin_amdgcn_mfma_f32_16x16x32_bf16(qf[ks], kf, s0, 0, 0, 0);
      }
      Sa[fj] = s0;
    }

    // Causal mask on the diagonal tile
    if (jt == qt) {
      #pragma unroll
      for (int fj = 0; fj < 4; ++fj)
        #pragma unroll
        for (int r = 0; r < 4; ++r) {
          int jg = fj * 16 + l15;
          int ig = w * 16 + l4 * 4 + r;
          if (jg > ig) Sa[fj][r] = -1e30f;
        }
    }

    // p = 2^(s' - m), store to LDS (wave-private rows, no barrier needed)
    #pragma unroll
    for (int fj = 0; fj < 4; ++fj)
      #pragma unroll
      for (int r = 0; r < 4; ++r)
        Ps[(w * 16 + l4 * 4 + r) * 72 + fj * 16 + l15] =
            f2bf(__builtin_exp2f(Sa[fj][r] - mh));

    // O += P V ; l += P . ones
    #pragma unroll
    for (int ks = 0; ks < 2; ++ks) {
      bf16x8 p0 = *(const bf16x8*)&Ps[(w * 16 + l15) * 72 + ks * 32 + l4 * 8];
      Ol = __builtin_amdgcn_mfma_f32_16x16x32_bf16(p0, ones, Ol, 0, 0, 0);
      #pragma unroll
      for (int fd = 0; fd < 8; ++fd) {
        bf16x8 vf = *(const bf16x8*)&Vts[(fd * 16 + l15) * 72 + ks * 32 + l4 * 8];
        Oa[fd] = __builtin_amdgcn_mfma_f32_16x16x32_bf16(p0, vf, Oa[fd], 0, 0, 0);
      }
    }
  }

  // Epilogue: O /= l, write bf16 [m][e]
  #pragma unroll
  for (int r = 0; r < 4; ++r) {
    float inv = 1.0f / Ol[r];
    int ig = i0 + w * 16 + l4 * 4 + r;
    #pragma unroll
    for (int fd = 0; fd < 8; ++fd)
      ao[(size_t)(b * 2048 + ig) * 2048 + h * 128 + fd * 16 + l15] =
          f2bf(Oa[fd][r] * inv);
  }
}

// ---------------------------------------------------------------------------
// Output GEMM: out[m][d] = sum_e ao[m][e] * WoutN[d][e], fp32 out.
// ---------------------------------------------------------------------------
__global__ __launch_bounds__(256) void gemm_out(
    const ushort* __restrict__ A, const ushort* __restrict__ Bw,
    float* __restrict__ C) {
  const int n0 = blockIdx.x * 128;
  const int m0 = blockIdx.y * 128;
  __shared__ __align__(16) ushort As[128 * 32];
  __shared__ __align__(16) ushort Bs[128 * 32];
  const int t = threadIdx.x, w = t >> 6, l = t & 63;
  const int wm = w & 1, wn = w >> 1;
  const int l15 = l & 15, l4 = l >> 4;

  f32x4 acc[4][4];
  #pragma unroll
  for (int i = 0; i < 4; ++i)
    #pragma unroll
    for (int j = 0; j < 4; ++j) acc[i][j] = (f32x4){0.f, 0.f, 0.f, 0.f};

  gemm_mainloop(A, Bw, m0, n0, As, Bs, acc, t, l, wm, wn);

  #pragma unroll
  for (int fm = 0; fm < 4; ++fm)
    #pragma unroll
    for (int fn = 0; fn < 4; ++fn)
      #pragma unroll
      for (int r = 0; r < 4; ++r)
        C[(size_t)(m0 + wm * 64 + fm * 16 + l4 * 4 + r) * 2048 +
          n0 + wn * 64 + fn * 16 + l15] = acc[fm][fn][r];
}

// ---------------------------------------------------------------------------
// Launch
// ---------------------------------------------------------------------------
extern "C" void kernel_launch(void* const* d_in, const int* in_sizes, int n_in,
                              void* d_out, int out_size, void* d_ws, size_t ws_size,
                              hipStream_t stream) {
  (void)in_sizes; (void)n_in; (void)out_size; (void)ws_size;
  const float* x    = (const float*)d_in[0];
  const float* Wq   = (const float*)d_in[1];
  const float* Wk   = (const float*)d_in[2];
  const float* Wv   = (const float*)d_in[3];
  const float* Wout = (const float*)d_in[4];
  const float* qks  = (const float*)d_in[5];
  char* ws = (char*)d_ws;

  ushort* wqn  = (ushort*)(ws + 0);           //  8 MB
  ushort* wkn  = (ushort*)(ws + 8388608);     //  8 MB
  ushort* wvn  = (ushort*)(ws + 16777216);    //  8 MB
  ushort* wotn = (ushort*)(ws + 25165824);    //  8 MB
  ushort* xbf  = (ushort*)(ws + 33554432);    // 16 MB
  ushort* qn   = (ushort*)(ws + 50331648);    // 16 MB
  ushort* kn   = (ushort*)(ws + 67108864);    // 16 MB
  ushort* vt   = (ushort*)(ws + 83886080);    // 16 MB
  ushort* ao   = (ushort*)(ws + 100663296);   // 16 MB
  float* colss = (float*)(ws + 117440512);    //  8 KB
  float* mh    = (float*)(ws + 117448704);    //  64 B
  float* out   = (float*)d_out;

  hipMemsetAsync(colss, 0, 2048 * sizeof(float), stream);
  prep_w_rows<<<dim3(2048, 3), 256, 0, stream>>>(Wq, Wk, Wv, wqn, wkn, wvn);
  wout_colss<<<dim3(8, 16), 256, 0, stream>>>(Wout, colss);
  wout_norm<<<4096, 256, 0, stream>>>(Wout, colss, wotn);
  convert_x<<<8192, 256, 0, stream>>>(x, xbf);
  qk_mhead<<<16, 64, 0, stream>>>(qks, mh);
  gemm_qkv<<<dim3(16, 32, 3), 256, 0, stream>>>(xbf, wqn, wkn, wvn, qks, qn, kn, vt);
  attn_kernel<<<dim3(32, 32), 256, 0, stream>>>(qn, kn, vt, mh, ao);
  gemm_out<<<dim3(16, 32), 256, 0, stream>>>(ao, wotn, out);
}

// Round 3
// 391.870 us; speedup vs baseline: 1.4667x; 1.0732x over previous
//
#include <hip/hip_runtime.h>

// ---------------------------------------------------------------------------
// nGPT attention block on MI355X (gfx950), bf16 MFMA pipeline.
// Sizes: DIM=2048, HEADS=16, DH=128, B=2, S=2048, M=B*S=4096.
// ---------------------------------------------------------------------------

typedef __bf16 bf16x8 __attribute__((ext_vector_type(8)));
typedef float f32x4 __attribute__((ext_vector_type(4)));

__device__ __forceinline__ unsigned short f2bf(float f) {
  unsigned int u = __float_as_uint(f);
  u = u + 0x7FFFu + ((u >> 16) & 1u);   // round-to-nearest-even
  return (unsigned short)(u >> 16);
}

__device__ __forceinline__ void async16(const void* g, void* l) {
  __builtin_amdgcn_global_load_lds(
      (const __attribute__((address_space(1))) unsigned int*)g,
      (__attribute__((address_space(3))) unsigned int*)l, 16, 0, 0);
}

// scale folded into q: qk_scale * DIM * sqrt(DH) * log2(e)
#define QFOLD (2048.0f * 11.313708498984761f * 1.4426950408889634f)

// ---------------------------------------------------------------------------
// Prep kernels
// ---------------------------------------------------------------------------

// Row-l2norm of Wq/Wk/Wv (2048 rows x 2048) -> bf16. grid (2048, 3), block 256.
__global__ __launch_bounds__(256) void prep_w_rows(
    const float* __restrict__ Wq, const float* __restrict__ Wk,
    const float* __restrict__ Wv, ushort* __restrict__ oq,
    ushort* __restrict__ ok_, ushort* __restrict__ ov) {
  const int row = blockIdx.x;
  const float* W = (blockIdx.y == 0) ? Wq : (blockIdx.y == 1) ? Wk : Wv;
  ushort* O = (blockIdx.y == 0) ? oq : (blockIdx.y == 1) ? ok_ : ov;
  const int t = threadIdx.x;
  const float4* Wr = (const float4*)(W + (size_t)row * 2048);
  float4 v0 = Wr[t];
  float4 v1 = Wr[t + 256];
  float ss = v0.x * v0.x + v0.y * v0.y + v0.z * v0.z + v0.w * v0.w +
             v1.x * v1.x + v1.y * v1.y + v1.z * v1.z + v1.w * v1.w;
  ss += __shfl_xor(ss, 1);  ss += __shfl_xor(ss, 2);
  ss += __shfl_xor(ss, 4);  ss += __shfl_xor(ss, 8);
  ss += __shfl_xor(ss, 16); ss += __shfl_xor(ss, 32);
  __shared__ float red[4];
  if ((t & 63) == 0) red[t >> 6] = ss;
  __syncthreads();
  float tot = red[0] + red[1] + red[2] + red[3];
  float sc = 1.0f / fmaxf(sqrtf(tot), 1e-12f);
  ushort4 o0, o1;
  o0.x = f2bf(v0.x * sc); o0.y = f2bf(v0.y * sc);
  o0.z = f2bf(v0.z * sc); o0.w = f2bf(v0.w * sc);
  o1.x = f2bf(v1.x * sc); o1.y = f2bf(v1.y * sc);
  o1.z = f2bf(v1.z * sc); o1.w = f2bf(v1.w * sc);
  *(ushort4*)(O + (size_t)row * 2048 + t * 4) = o0;
  *(ushort4*)(O + (size_t)row * 2048 + 1024 + t * 4) = o1;
}

// Wout column sum-of-squares. grid (8, 16), block 256. colss pre-zeroed.
__global__ __launch_bounds__(256) void wout_colss(const float* __restrict__ W,
                                                  float* __restrict__ colss) {
  const int e = blockIdx.x * 256 + threadIdx.x;
  const int d0 = blockIdx.y * 128;
  float ss = 0.f;
  #pragma unroll 8
  for (int i = 0; i < 128; ++i) {
    float v = W[(size_t)(d0 + i) * 2048 + e];
    ss += v * v;
  }
  atomicAdd(colss + e, ss);
}

// Wout / colnorm -> bf16. grid 4096, block 256, 4 elems/thread.
__global__ __launch_bounds__(256) void wout_norm(const float* __restrict__ W,
                                                 const float* __restrict__ colss,
                                                 ushort* __restrict__ O) {
  const int idx = (blockIdx.x * 256 + threadIdx.x) * 4;
  float4 v = *(const float4*)(W + idx);
  float4 c = *(const float4*)(colss + (idx & 2047));
  ushort4 o;
  o.x = f2bf(v.x / fmaxf(sqrtf(c.x), 1e-12f));
  o.y = f2bf(v.y / fmaxf(sqrtf(c.y), 1e-12f));
  o.z = f2bf(v.z / fmaxf(sqrtf(c.z), 1e-12f));
  o.w = f2bf(v.w / fmaxf(sqrtf(c.w), 1e-12f));
  *(ushort4*)(O + idx) = o;
}

// x fp32 -> bf16. grid 8192, block 256, 4 elems/thread (8M total).
__global__ __launch_bounds__(256) void convert_x(const float* __restrict__ X,
                                                 ushort* __restrict__ O) {
  const int idx = (blockIdx.x * 256 + threadIdx.x) * 4;
  float4 v = *(const float4*)(X + idx);
  ushort4 o;
  o.x = f2bf(v.x); o.y = f2bf(v.y); o.z = f2bf(v.z); o.w = f2bf(v.w);
  *(ushort4*)(O + idx) = o;
}

// Per-head softmax max-bound: m[h] = QFOLD * max_d |qks[h*128+d]|. grid 16, block 64.
__global__ __launch_bounds__(64) void qk_mhead(const float* __restrict__ qks,
                                               float* __restrict__ mh) {
  const int h = blockIdx.x, l = threadIdx.x;
  float m = fmaxf(fabsf(qks[h * 128 + l]), fabsf(qks[h * 128 + 64 + l]));
  m = fmaxf(m, __shfl_xor(m, 1));  m = fmaxf(m, __shfl_xor(m, 2));
  m = fmaxf(m, __shfl_xor(m, 4));  m = fmaxf(m, __shfl_xor(m, 8));
  m = fmaxf(m, __shfl_xor(m, 16)); m = fmaxf(m, __shfl_xor(m, 32));
  if (l == 0) mh[h] = m * QFOLD;
}

// ---------------------------------------------------------------------------
// Shared GEMM mainloop: C[128x128] = A[128xK] * B[128xK]^T, K=2048, BK=64.
// LDS rows padded: 8 data chunks + 1 pad chunk (144B stride -> conflict-free
// 2-way aliasing). Staging lane-linear for global_load_lds; pad lanes redo
// chunk 0 of their row (L1-hit dummy). 32 MFMA per barrier-pair.
// ---------------------------------------------------------------------------
__device__ __forceinline__ void gemm_mainloop(
    const ushort* __restrict__ A, const ushort* __restrict__ Bw,
    int m0, int n0, ushort* As, ushort* Bs, f32x4 acc[4][4],
    int t, int l, int wm, int wn) {
  const int l15 = l & 15, l4 = l >> 4;
  const ushort* abase = A + (size_t)m0 * 2048;
  const ushort* bbase = Bw + (size_t)n0 * 2048;
  for (int kt = 0; kt < 32; ++kt) {
    const int k0 = kt * 64;
    __syncthreads();
    // 2 tiles x 128 rows x 9 chunks (8 data + 1 pad-dummy) = 2304 chunks
    #pragma unroll
    for (int p = 0; p < 9; ++p) {
      int c = p * 256 + t;
      const ushort* src = abase;
      char* dst = (char*)As;
      int cc = c;
      if (c >= 1152) { cc = c - 1152; src = bbase; dst = (char*)Bs; }
      int r = cc / 9, dc = cc - r * 9;
      int dcc = (dc == 8) ? 0 : dc;
      async16(src + (size_t)r * 2048 + k0 + dcc * 8, dst + cc * 16);
    }
    __syncthreads();
    #pragma unroll
    for (int ks = 0; ks < 2; ++ks) {
      bf16x8 af[4], bg[4];
      #pragma unroll
      for (int f = 0; f < 4; ++f)
        af[f] = *(const bf16x8*)&As[(wm * 64 + f * 16 + l15) * 72 + ks * 32 + l4 * 8];
      #pragma unroll
      for (int f = 0; f < 4; ++f)
        bg[f] = *(const bf16x8*)&Bs[(wn * 64 + f * 16 + l15) * 72 + ks * 32 + l4 * 8];
      #pragma unroll
      for (int fm = 0; fm < 4; ++fm)
        #pragma unroll
        for (int fn = 0; fn < 4; ++fn)
          acc[fm][fn] = __builtin_amdgcn_mfma_f32_16x16x32_bf16(
              af[fm], bg[fn], acc[fm][fn], 0, 0, 0);
    }
  }
}

// ---------------------------------------------------------------------------
// QKV GEMM with fused per-head l2norm epilogue.
// z=0: q -> l2norm * qk_scale*DIM*sqrt(128)*log2e, bf16 [m][e]
// z=1: k -> l2norm, bf16 [m][e]
// z=2: v -> bf16 transposed [b,h,d][n]
// ---------------------------------------------------------------------------
__global__ __launch_bounds__(256, 4) void gemm_qkv(
    const ushort* __restrict__ X, const ushort* __restrict__ Wq,
    const ushort* __restrict__ Wk, const ushort* __restrict__ Wv,
    const float* __restrict__ qks, ushort* __restrict__ qn,
    ushort* __restrict__ kn, ushort* __restrict__ vt) {
  const int z = blockIdx.z;
  const ushort* Bw = (z == 0) ? Wq : (z == 1) ? Wk : Wv;
  const int n0 = blockIdx.x * 128;
  const int m0 = blockIdx.y * 128;
  __shared__ __align__(16) ushort As[128 * 72];
  __shared__ __align__(16) ushort Bs[128 * 72];
  __shared__ float partials[2][128];
  const int t = threadIdx.x, w = t >> 6, l = t & 63;
  const int wm = w & 1, wn = w >> 1;
  const int l15 = l & 15, l4 = l >> 4;

  f32x4 acc[4][4];
  #pragma unroll
  for (int i = 0; i < 4; ++i)
    #pragma unroll
    for (int j = 0; j < 4; ++j) acc[i][j] = (f32x4){0.f, 0.f, 0.f, 0.f};

  gemm_mainloop(X, Bw, m0, n0, As, Bs, acc, t, l, wm, wn);

  const int h = n0 >> 7;
  if (z == 2) {
    #pragma unroll
    for (int fm = 0; fm < 4; ++fm) {
      int mrow = m0 + wm * 64 + fm * 16 + l4 * 4;
      int bb = mrow >> 11;
      int nn = mrow & 2047;
      #pragma unroll
      for (int fn = 0; fn < 4; ++fn) {
        int d = wn * 64 + fn * 16 + l15;
        ushort4 p;
        p.x = f2bf(acc[fm][fn][0]); p.y = f2bf(acc[fm][fn][1]);
        p.z = f2bf(acc[fm][fn][2]); p.w = f2bf(acc[fm][fn][3]);
        *(ushort4*)(vt + (size_t)((bb * 16 + h) * 128 + d) * 2048 + nn) = p;
      }
    }
  } else {
    float rs[4][4];
    #pragma unroll
    for (int fm = 0; fm < 4; ++fm)
      #pragma unroll
      for (int r = 0; r < 4; ++r) {
        float s = 0.f;
        #pragma unroll
        for (int fn = 0; fn < 4; ++fn) {
          float v = acc[fm][fn][r];
          s += v * v;
        }
        s += __shfl_xor(s, 1); s += __shfl_xor(s, 2);
        s += __shfl_xor(s, 4); s += __shfl_xor(s, 8);
        rs[fm][r] = s;
      }
    if (l15 == 0) {
      #pragma unroll
      for (int fm = 0; fm < 4; ++fm)
        #pragma unroll
        for (int r = 0; r < 4; ++r)
          partials[wn][wm * 64 + fm * 16 + l4 * 4 + r] = rs[fm][r];
    }
    __syncthreads();
    float cs[4];
    #pragma unroll
    for (int fn = 0; fn < 4; ++fn)
      cs[fn] = (z == 0) ? qks[n0 + wn * 64 + fn * 16 + l15] * QFOLD : 1.0f;
    ushort* O = (z == 0) ? qn : kn;
    #pragma unroll
    for (int fm = 0; fm < 4; ++fm)
      #pragma unroll
      for (int r = 0; r < 4; ++r) {
        int i = wm * 64 + fm * 16 + l4 * 4 + r;
        float tot = partials[0][i] + partials[1][i];
        float sc = 1.0f / fmaxf(sqrtf(tot), 1e-12f);
        #pragma unroll
        for (int fn = 0; fn < 4; ++fn)
          O[(size_t)(m0 + i) * 2048 + n0 + wn * 64 + fn * 16 + l15] =
              f2bf(acc[fm][fn][r] * sc * cs[fn]);
      }
  }
}

// ---------------------------------------------------------------------------
// Causal flash attention, fixed-m softmax (m bounded per head from qk_scale).
// grid (hb=32, qtile=32) with qt reversed (heavy blocks dispatch first).
// 64-row Q tiles (16 rows/wave), KV-tile 64. Row-sum l via MFMA vs ones.
// ---------------------------------------------------------------------------
__global__ __launch_bounds__(256, 3) void attn_kernel(
    const ushort* __restrict__ qn, const ushort* __restrict__ kn,
    const ushort* __restrict__ vt, const float* __restrict__ mhead,
    ushort* __restrict__ ao) {
  const int hb = blockIdx.x;
  const int b = hb >> 4, h = hb & 15;
  const int qt = 31 - blockIdx.y;          // LPT: heavy first
  const int i0 = qt * 64;
  const int t = threadIdx.x, w = t >> 6, l = t & 63;
  const int l15 = l & 15, l4 = l >> 4;

  __shared__ __align__(16) ushort Ks[64 * 136];
  __shared__ __align__(16) ushort Vts[128 * 72];
  __shared__ __align__(16) ushort Ps[64 * 72];

  bf16x8 qf[4];
  #pragma unroll
  for (int ks = 0; ks < 4; ++ks)
    qf[ks] = *(const bf16x8*)(qn +
        (size_t)(b * 2048 + i0 + w * 16 + l15) * 2048 +
        h * 128 + ks * 32 + l4 * 8);

  f32x4 Oa[8];
  #pragma unroll
  for (int fd = 0; fd < 8; ++fd) Oa[fd] = (f32x4){0.f, 0.f, 0.f, 0.f};
  f32x4 Ol = (f32x4){0.f, 0.f, 0.f, 0.f};

  const float mh = mhead[h];
  const __bf16 one = (__bf16)1.0f;
  const bf16x8 ones = {one, one, one, one, one, one, one, one};

  const ushort* kbase = kn + (size_t)(b * 2048) * 2048 + h * 128;
  const ushort* vbase = vt + (size_t)((b * 16 + h) * 128) * 2048;

  for (int jt = 0; jt <= qt; ++jt) {
    const int j0 = jt * 64;
    __syncthreads();
    #pragma unroll
    for (int pass = 0; pass < 5; ++pass) {
      int c = pass * 256 + t;
      if (c < 1088) {
        int r = c / 17, dc = c - r * 17;
        int dcc = (dc == 16) ? 0 : dc;
        async16(kbase + (size_t)(j0 + r) * 2048 + dcc * 8, (char*)Ks + c * 16);
      }
    }
    #pragma unroll
    for (int pass = 0; pass < 5; ++pass) {
      int c = pass * 256 + t;
      if (c < 1152) {
        int r = c / 9, jc = c - r * 9;
        int jcc = (jc == 8) ? 0 : jc;
        async16(vbase + (size_t)r * 2048 + j0 + jcc * 8, (char*)Vts + c * 16);
      }
    }
    __syncthreads();

    f32x4 Sa[4];
    #pragma unroll
    for (int fj = 0; fj < 4; ++fj) {
      f32x4 s0 = (f32x4){0.f, 0.f, 0.f, 0.f};
      #pragma unroll
      for (int ks = 0; ks < 4; ++ks) {
        bf16x8 kf = *(const bf16x8*)&Ks[(fj * 16 + l15) * 136 + ks * 32 + l4 * 8];
        s0 = __builtin_amdgcn_mfma_f32_16x16x32_bf16(qf[ks], kf, s0, 0, 0, 0);
      }
      Sa[fj] = s0;
    }

    if (jt == qt) {
      #pragma unroll
      for (int fj = 0; fj < 4; ++fj)
        #pragma unroll
        for (int r = 0; r < 4; ++r) {
          int jg = fj * 16 + l15;
          int ig = w * 16 + l4 * 4 + r;
          if (jg > ig) Sa[fj][r] = -1e30f;
        }
    }

    #pragma unroll
    for (int fj = 0; fj < 4; ++fj)
      #pragma unroll
      for (int r = 0; r < 4; ++r)
        Ps[(w * 16 + l4 * 4 + r) * 72 + fj * 16 + l15] =
            f2bf(__builtin_exp2f(Sa[fj][r] - mh));

    #pragma unroll
    for (int ks = 0; ks < 2; ++ks) {
      bf16x8 p0 = *(const bf16x8*)&Ps[(w * 16 + l15) * 72 + ks * 32 + l4 * 8];
      Ol = __builtin_amdgcn_mfma_f32_16x16x32_bf16(p0, ones, Ol, 0, 0, 0);
      #pragma unroll
      for (int fd = 0; fd < 8; ++fd) {
        bf16x8 vf = *(const bf16x8*)&Vts[(fd * 16 + l15) * 72 + ks * 32 + l4 * 8];
        Oa[fd] = __builtin_amdgcn_mfma_f32_16x16x32_bf16(p0, vf, Oa[fd], 0, 0, 0);
      }
    }
  }

  #pragma unroll
  for (int r = 0; r < 4; ++r) {
    float inv = 1.0f / Ol[r];
    int ig = i0 + w * 16 + l4 * 4 + r;
    #pragma unroll
    for (int fd = 0; fd < 8; ++fd)
      ao[(size_t)(b * 2048 + ig) * 2048 + h * 128 + fd * 16 + l15] =
          f2bf(Oa[fd][r] * inv);
  }
}

// ---------------------------------------------------------------------------
// Output GEMM: out[m][d] = sum_e ao[m][e] * WoutN[d][e], fp32 out.
// ---------------------------------------------------------------------------
__global__ __launch_bounds__(256, 4) void gemm_out(
    const ushort* __restrict__ A, const ushort* __restrict__ Bw,
    float* __restrict__ C) {
  const int n0 = blockIdx.x * 128;
  const int m0 = blockIdx.y * 128;
  __shared__ __align__(16) ushort As[128 * 72];
  __shared__ __align__(16) ushort Bs[128 * 72];
  const int t = threadIdx.x, w = t >> 6, l = t & 63;
  const int wm = w & 1, wn = w >> 1;
  const int l15 = l & 15, l4 = l >> 4;

  f32x4 acc[4][4];
  #pragma unroll
  for (int i = 0; i < 4; ++i)
    #pragma unroll
    for (int j = 0; j < 4; ++j) acc[i][j] = (f32x4){0.f, 0.f, 0.f, 0.f};

  gemm_mainloop(A, Bw, m0, n0, As, Bs, acc, t, l, wm, wn);

  #pragma unroll
  for (int fm = 0; fm < 4; ++fm)
    #pragma unroll
    for (int fn = 0; fn < 4; ++fn)
      #pragma unroll
      for (int r = 0; r < 4; ++r)
        C[(size_t)(m0 + wm * 64 + fm * 16 + l4 * 4 + r) * 2048 +
          n0 + wn * 64 + fn * 16 + l15] = acc[fm][fn][r];
}

// ---------------------------------------------------------------------------
// Launch
// ---------------------------------------------------------------------------
extern "C" void kernel_launch(void* const* d_in, const int* in_sizes, int n_in,
                              void* d_out, int out_size, void* d_ws, size_t ws_size,
                              hipStream_t stream) {
  (void)in_sizes; (void)n_in; (void)out_size; (void)ws_size;
  const float* x    = (const float*)d_in[0];
  const float* Wq   = (const float*)d_in[1];
  const float* Wk   = (const float*)d_in[2];
  const float* Wv   = (const float*)d_in[3];
  const float* Wout = (const float*)d_in[4];
  const float* qks  = (const float*)d_in[5];
  char* ws = (char*)d_ws;

  ushort* wqn  = (ushort*)(ws + 0);           //  8 MB
  ushort* wkn  = (ushort*)(ws + 8388608);     //  8 MB
  ushort* wvn  = (ushort*)(ws + 16777216);    //  8 MB
  ushort* wotn = (ushort*)(ws + 25165824);    //  8 MB
  ushort* xbf  = (ushort*)(ws + 33554432);    // 16 MB
  ushort* qn   = (ushort*)(ws + 50331648);    // 16 MB
  ushort* kn   = (ushort*)(ws + 67108864);    // 16 MB
  ushort* vt   = (ushort*)(ws + 83886080);    // 16 MB
  ushort* ao   = (ushort*)(ws + 100663296);   // 16 MB
  float* colss = (float*)(ws + 117440512);    //  8 KB
  float* mh    = (float*)(ws + 117448704);    //  64 B
  float* out   = (float*)d_out;

  hipMemsetAsync(colss, 0, 2048 * sizeof(float), stream);
  prep_w_rows<<<dim3(2048, 3), 256, 0, stream>>>(Wq, Wk, Wv, wqn, wkn, wvn);
  wout_colss<<<dim3(8, 16), 256, 0, stream>>>(Wout, colss);
  wout_norm<<<4096, 256, 0, stream>>>(Wout, colss, wotn);
  convert_x<<<8192, 256, 0, stream>>>(x, xbf);
  qk_mhead<<<16, 64, 0, stream>>>(qks, mh);
  gemm_qkv<<<dim3(16, 32, 3), 256, 0, stream>>>(xbf, wqn, wkn, wvn, qks, qn, kn, vt);
  attn_kernel<<<dim3(32, 32), 256, 0, stream>>>(qn, kn, vt, mh, ao);
  gemm_out<<<dim3(16, 32), 256, 0, stream>>>(ao, wotn, out);
}